// Round 9
// baseline (325.532 us; speedup 1.0000x reference)
//
#include <hip/hip_runtime.h>

#define TS 3584
#define VS 1792
#define TPF 448
#define NHEAD 12
#define HDIM 128
#define DMODEL 1536
// ATTN_SCALE * log2(e): folded into q during rmsnorm_rope so QK^T scores are
// already in log2 domain (softmax uses exp2).
#define QK_PRESCALE (0.08838834764831845f * 1.4426950408889634f)

typedef unsigned short u16;
typedef unsigned int u32;
typedef unsigned long long u64;
typedef __attribute__((ext_vector_type(8))) short bf16x8;
typedef __attribute__((ext_vector_type(4))) float f32x4;

__device__ __forceinline__ float u2f(u32 u) { union { u32 u; float f; } c; c.u = u; return c.f; }
__device__ __forceinline__ float blo(u32 u) { return u2f(u << 16); }
__device__ __forceinline__ float bhi(u32 u) { return u2f(u & 0xffff0000u); }
__device__ __forceinline__ u16 f2b(float f) {
  union { float f; u32 u; } c; c.f = f;
  return (u16)((c.u + 0x7fffu + ((c.u >> 16) & 1u)) >> 16);
}

__device__ __forceinline__ float exp2fast(float x) {
#if __has_builtin(__builtin_amdgcn_exp2f)
  return __builtin_amdgcn_exp2f(x);
#else
  float r; asm("v_exp_f32 %0, %1" : "=v"(r) : "v"(x)); return r;
#endif
}

// async global -> LDS, 16B per lane; LDS dest is wave-uniform base
// (HW writes base + lane*16), global src is per-lane (pre-swizzled).
__device__ __forceinline__ void gl16(const u16* g, u16* l) {
  __builtin_amdgcn_global_load_lds(
      (const __attribute__((address_space(1))) void*)g,
      (__attribute__((address_space(3))) void*)l, 16, 0, 0);
}

// Pack fp32 tensors to bf16 (RNE). z: 0=x, 1..3=q/k/v weights (concat), 4=o_w.
__global__ __launch_bounds__(256) void convert_bf16(
    const float* __restrict__ x, const float* __restrict__ qw,
    const float* __restrict__ kw, const float* __restrict__ vw,
    const float* __restrict__ ow, u16* __restrict__ xb,
    u16* __restrict__ wqkv, u16* __restrict__ owb) {
  const int z = blockIdx.y;
  const float* src;
  u16* dst;
  int n8;
  if (z == 0)      { src = x;  dst = xb;  n8 = TS * DMODEL / 8; }
  else if (z == 4) { src = ow; dst = owb; n8 = DMODEL * DMODEL / 8; }
  else {
    src = (z == 1) ? qw : (z == 2) ? kw : vw;
    dst = wqkv + (size_t)(z - 1) * DMODEL * DMODEL;
    n8 = DMODEL * DMODEL / 8;
  }
  const int idx = blockIdx.x * 256 + threadIdx.x;
  if (idx >= n8) return;
  const float4 a = ((const float4*)src)[2 * idx];
  const float4 b = ((const float4*)src)[2 * idx + 1];
  uint4 o;
  o.x = (u32)f2b(a.x) | ((u32)f2b(a.y) << 16);
  o.y = (u32)f2b(a.z) | ((u32)f2b(a.w) << 16);
  o.z = (u32)f2b(b.x) | ((u32)f2b(b.y) << 16);
  o.w = (u32)f2b(b.z) | ((u32)f2b(b.w) << 16);
  ((uint4*)dst)[idx] = o;
}

// QKV GEMM: C[m,n] = sum_k A[m,k]*W[n,k] + bias[n]. 256x128 tile, BK=64,
// 512 thr = 8 waves (4M x 2N), wave-tile 64x64 via 4x4 mfma 16x16x32.
// Staging via global_load_lds (pre-swizzled global src) + bijective XCD swizzle.
// BN=128 keeps each block inside one q/k/v section; v-section blocks write vt
// TRANSPOSED via a two-half swizzled LDS bounce (no separate transpose kernel).
__global__ __launch_bounds__(512) void gemm_qkv(
    const u16* __restrict__ A, const u16* __restrict__ W,
    const float* __restrict__ b0, const float* __restrict__ b1,
    const float* __restrict__ b2,
    u16* __restrict__ o0, u16* __restrict__ o1, u16* __restrict__ o2) {
  __shared__ __align__(16) u16 Als[256 * 64];   // 32 KB (reused by v-epilogue)
  __shared__ __align__(16) u16 Bls[128 * 64];   // 16 KB
  const int t = threadIdx.x;
  const int wave = t >> 6, lane = t & 63, col = lane & 15, quad = lane >> 4;
  // XCD swizzle (nwg = 36*14 = 504, divisible by 8 -> bijective).
  const int nwg = gridDim.x * gridDim.y;
  const int dlin = blockIdx.y * gridDim.x + blockIdx.x;
  const int wk = (dlin & 7) * (nwg >> 3) + (dlin >> 3);
  const int by = wk / gridDim.x, bx = wk - by * gridDim.x;
  const int m0 = by * 256, n0 = bx * 128;
  const int wm = (wave & 3) * 64, wn = (wave >> 2) * 64;

  // per-lane pre-swizzled staging sources: LDS linear dest idx*8 holds
  // global chunk (idx&7)^((idx>>3)&7) of row idx>>3 (matches read swizzle).
  const u16* pA[4];
  const u16* pB[2];
#pragma unroll
  for (int i = 0; i < 4; ++i) {
    const int idx = t + i * 512;
    const int r = idx >> 3, sch = (idx & 7) ^ (r & 7);
    pA[i] = A + (size_t)(m0 + r) * DMODEL + sch * 8;
  }
#pragma unroll
  for (int i = 0; i < 2; ++i) {
    const int idx = t + i * 512;
    const int r = idx >> 3, sch = (idx & 7) ^ (r & 7);
    pB[i] = W + (size_t)(n0 + r) * DMODEL + sch * 8;
  }

  f32x4 acc[4][4];
#pragma unroll
  for (int i = 0; i < 4; ++i)
#pragma unroll
    for (int j = 0; j < 4; ++j) acc[i][j] = (f32x4){0.f, 0.f, 0.f, 0.f};

  for (int k0 = 0; k0 < DMODEL; k0 += 64) {
    __syncthreads();
#pragma unroll
    for (int i = 0; i < 4; ++i)
      gl16(pA[i] + k0, &Als[i * 4096 + wave * 512]);
#pragma unroll
    for (int i = 0; i < 2; ++i)
      gl16(pB[i] + k0, &Bls[i * 4096 + wave * 512]);
    __syncthreads();   // compiler drains vmcnt before s_barrier
#pragma unroll
    for (int s = 0; s < 2; ++s) {
      bf16x8 af[4], bv[4];
#pragma unroll
      for (int i = 0; i < 4; ++i) {
        const int r = wm + i * 16 + col;
        af[i] = *(const bf16x8*)&Als[r * 64 + (((s * 4 + quad) ^ (r & 7)) * 8)];
      }
#pragma unroll
      for (int j = 0; j < 4; ++j) {
        const int r = wn + j * 16 + col;
        bv[j] = *(const bf16x8*)&Bls[r * 64 + (((s * 4 + quad) ^ (r & 7)) * 8)];
      }
#pragma unroll
      for (int i = 0; i < 4; ++i)
#pragma unroll
        for (int j = 0; j < 4; ++j)
          acc[i][j] = __builtin_amdgcn_mfma_f32_16x16x32_bf16(af[i], bv[j], acc[i][j], 0, 0, 0);
    }
  }

  const int sec = n0 / DMODEL;   // block-uniform (BN=128 within one section)
  if (sec == 2) {
    // ---- fused V transpose: two 128-token halves through Als bounce ----
    const int hgl = (n0 - 2 * DMODEL) >> 7;        // global head
#pragma unroll
    for (int hh = 0; hh < 2; ++hh) {
      __syncthreads();   // waves done reading Als (or done with prev half)
      if (((wave & 3) >> 1) == hh) {
#pragma unroll
        for (int j = 0; j < 4; ++j) {
          const int hdl = wn + j * 16 + col;       // 0..127 (head-local hd)
          const float bias = b2[n0 - 2 * DMODEL + hdl];
#pragma unroll
          for (int i = 0; i < 4; ++i) {
            const int tl = (wm & 127) + i * 16 + quad * 4;   // 0..124
            u64 pk = (u64)f2b(acc[i][j][0] + bias) |
                     ((u64)f2b(acc[i][j][1] + bias) << 16) |
                     ((u64)f2b(acc[i][j][2] + bias) << 32) |
                     ((u64)f2b(acc[i][j][3] + bias) << 48);
            *(u64*)&Als[hdl * 128 + (((tl >> 3) ^ (hdl & 15)) * 8) + (tl & 7)] = pk;
          }
        }
      }
      __syncthreads();
#pragma unroll
      for (int it = 0; it < 4; ++it) {
        const int idx = t + it * 512;
        const int row = idx >> 4, ch = idx & 15;
        uint4 w4 = *(const uint4*)&Als[row * 128 + ((ch ^ (row & 15)) * 8)];
        *(uint4*)(o2 + (size_t)(hgl * HDIM + row) * TS + m0 + hh * 128 + ch * 8) = w4;
      }
    }
    return;
  }
  // ---- q / k sections: row-major bf16 + bias ----
  u16* dst = (sec == 0) ? o0 : o1;
  const float* bp = (sec == 0) ? b0 : b1;
#pragma unroll
  for (int j = 0; j < 4; ++j) {
    const int nn = n0 - sec * DMODEL + wn + j * 16 + col;
    const float bias = bp[nn];
#pragma unroll
    for (int i = 0; i < 4; ++i) {
      const int mb = m0 + wm + i * 16 + quad * 4;
#pragma unroll
      for (int r = 0; r < 4; ++r)
        dst[(size_t)(mb + r) * DMODEL + nn] = f2b(acc[i][j][r] + bias);
    }
  }
}

// Output GEMM: of[m,n] = sum_k A[m,k]*W[n,k] + bias[n], fp32 out. 128x128 tile,
// BK=64, 256 thr = 4 waves, wave 64x64. gl16 staging + bijective XCD swizzle.
__global__ __launch_bounds__(256) void gemm_out(
    const u16* __restrict__ A, const u16* __restrict__ W,
    const float* __restrict__ b0, float* __restrict__ of) {
  __shared__ __align__(16) u16 Als[128 * 64];
  __shared__ __align__(16) u16 Bls[128 * 64];
  const int t = threadIdx.x;
  const int wave = t >> 6, lane = t & 63, col = lane & 15, quad = lane >> 4;
  const int nwg = gridDim.x * gridDim.y;   // 336, divisible by 8
  const int dlin = blockIdx.y * gridDim.x + blockIdx.x;
  const int wk = (dlin & 7) * (nwg >> 3) + (dlin >> 3);
  const int by = wk / gridDim.x, bx = wk - by * gridDim.x;
  const int m0 = by * 128, n0 = bx * 128;
  const int wm = (wave & 1) * 64, wn = (wave >> 1) * 64;

  const int srow = lane >> 3;
  const int sch = (lane & 7) ^ srow;
  const u16* pA[4];
  const u16* pB[4];
#pragma unroll
  for (int i = 0; i < 4; ++i) {
    const int r = i * 32 + wave * 8 + srow;
    pA[i] = A + (size_t)(m0 + r) * DMODEL + sch * 8;
    pB[i] = W + (size_t)(n0 + r) * DMODEL + sch * 8;
  }

  f32x4 acc[4][4];
#pragma unroll
  for (int i = 0; i < 4; ++i)
#pragma unroll
    for (int j = 0; j < 4; ++j) acc[i][j] = (f32x4){0.f, 0.f, 0.f, 0.f};

  for (int k0 = 0; k0 < DMODEL; k0 += 64) {
    __syncthreads();
#pragma unroll
    for (int i = 0; i < 4; ++i) {
      gl16(pA[i] + k0, &Als[i * 2048 + wave * 512]);
      gl16(pB[i] + k0, &Bls[i * 2048 + wave * 512]);
    }
    __syncthreads();
#pragma unroll
    for (int s = 0; s < 2; ++s) {
      bf16x8 af[4], bv[4];
#pragma unroll
      for (int i = 0; i < 4; ++i) {
        const int r = wm + i * 16 + col;
        af[i] = *(const bf16x8*)&Als[r * 64 + (((s * 4 + quad) ^ (r & 7)) * 8)];
      }
#pragma unroll
      for (int j = 0; j < 4; ++j) {
        const int r = wn + j * 16 + col;
        bv[j] = *(const bf16x8*)&Bls[r * 64 + (((s * 4 + quad) ^ (r & 7)) * 8)];
      }
#pragma unroll
      for (int i = 0; i < 4; ++i)
#pragma unroll
        for (int j = 0; j < 4; ++j)
          acc[i][j] = __builtin_amdgcn_mfma_f32_16x16x32_bf16(af[i], bv[j], acc[i][j], 0, 0, 0);
    }
  }

#pragma unroll
  for (int j = 0; j < 4; ++j) {
    const int ng = n0 + wn + j * 16 + col;
    const float bias = b0[ng];
#pragma unroll
    for (int i = 0; i < 4; ++i) {
      const int mb = m0 + wm + i * 16 + quad * 4;
#pragma unroll
      for (int r = 0; r < 4; ++r)
        of[(size_t)(mb + r) * DMODEL + ng] = acc[i][j][r] + bias;
    }
  }
}

// In-place RMSNorm(+weight) then RoPE on bf16 rows. blockIdx.x = token; y: 0=q,1=k.
__global__ __launch_bounds__(256) void rmsnorm_rope(
    u16* qbuf, u16* kbuf, const float* __restrict__ freqs,
    const float* __restrict__ nqw, const float* __restrict__ nkw) {
  const int tok = blockIdx.x;
  u32* row = (u32*)((blockIdx.y == 0 ? qbuf : kbuf) + (size_t)tok * DMODEL);
  const float* w = blockIdx.y == 0 ? nqw : nkw;
  const int t = threadIdx.x;
  const u32 u0 = row[t], u1 = row[t + 256], u2 = row[t + 512];
  float px[3] = { blo(u0), blo(u1), blo(u2) };
  float py[3] = { bhi(u0), bhi(u1), bhi(u2) };
  float ss = px[0] * px[0] + py[0] * py[0] + px[1] * px[1] + py[1] * py[1] +
             px[2] * px[2] + py[2] * py[2];
#pragma unroll
  for (int off = 32; off; off >>= 1) ss += __shfl_xor(ss, off);
  __shared__ float red[4];
  if ((t & 63) == 0) red[t >> 6] = ss;
  __syncthreads();
  float rstd = rsqrtf((red[0] + red[1] + red[2] + red[3]) * (1.0f / DMODEL) + 1e-6f);
  if (blockIdx.y == 0) rstd *= QK_PRESCALE;
  const int p = tok % VS;
  const int fi = p / TPF, rem = p % TPF, hi = rem / 28, wi = rem % 28;
#pragma unroll
  for (int jj = 0; jj < 3; ++jj) {
    const int pj = t + jj * 256;
    const int i = pj & 63;
    const int prow = (i < 22) ? fi : ((i < 43) ? hi : wi);
    const float ang = freqs[prow * 64 + i];
    float sn, cs;
    sincosf(ang, &sn, &cs);
    const float a = px[jj] * rstd * w[2 * pj], b = py[jj] * rstd * w[2 * pj + 1];
    row[pj] = (u32)f2b(a * cs - b * sn) | ((u32)f2b(a * sn + b * cs) << 16);
  }
}

// MFMA flash attention over union key set (in-view 1792 + cross-view same-frame 448).
// v8-exact (best measured ~105 us): KVBLK=32, K AND V double-buffered
// (prefetch distance = 1 full iteration, 2-barrier schedule), Q in registers
// (LDS 32KB), unroll x2 (compile-time buffer index), in-register P via permuted
// K rows, exp2 softmax, defer-max, setprio.
__global__ __launch_bounds__(256) void attn_mfma(
    const u16* __restrict__ q, const u16* __restrict__ k,
    const u16* __restrict__ vt, u16* __restrict__ fused) {
  __shared__ __align__(16) u16 Kls[2 * 32 * 128];   // 2 bufs x 8KB
  __shared__ __align__(16) u16 Vls[2 * 128 * 32];   // 2 bufs x 8KB
  const int t = threadIdx.x;
  const int wave = t >> 6, lane = t & 63;
  const int col = lane & 15, quad = lane >> 4;
  // XCD swizzle: 672 blocks = 8 XCDs x 84; each XCD gets a contiguous run of
  // (head, qblock) so its private L2 holds ~1.5 heads of K/V (~2.8 MB).
  const int d = blockIdx.y * 56 + blockIdx.x;
  const int wk = (d & 7) * 84 + (d >> 3);
  const int h = wk / 56;
  const int qb = wk - h * 56;
  const int q0 = qb * 64;
  const int vview = q0 / VS;
  const int fidx = (q0 % VS) / TPF;
  const int base0 = vview * VS;
  const int base1 = (1 - vview) * VS + fidx * TPF;
  const int jmpd = base1 - base0 - 1760;   // tile55 -> tile56 token delta

  // ---- Q fragments straight from global ----
  bf16x8 qfrag[4];
#pragma unroll
  for (int c = 0; c < 4; ++c)
    qfrag[c] = *(const bf16x8*)(q + (size_t)(q0 + wave * 16 + col) * DMODEL +
                                h * HDIM + ((c * 4 + quad) << 3));
  asm volatile("" ::: "memory");   // pin Q loads before K staging (vmcnt order)

  // ---- per-lane staging sources (pre-swizzled) ----
  // K: chunk swizzle k4(key)=((key>>1)&12)|(key&3); permuted read rows
  // pi(col), pi(col)+4 see XOR key4 == col -> s0/s1 = keys 8*quad..8*quad+7.
  const u16* ksrc[2];
  const u16* vsrc[2];
#pragma unroll
  for (int j = 0; j < 2; ++j) {
    const int ci = (wave * 2 + j) * 64 + lane;    // 0..511
    const int key = ci >> 4, c = ci & 15;         // key 0..31
    const int k4 = ((key >> 1) & 12) | (key & 3);
    ksrc[j] = k + (size_t)(base0 + key) * DMODEL + h * HDIM + ((c ^ k4) << 3);
    const int hd = ci >> 2, sl = ci & 3;          // hd 0..127
    vsrc[j] = vt + (size_t)(h * HDIM + hd) * TS + base0 + ((sl ^ (hd & 3)) << 3);
  }
  // loop-invariant LDS read offsets (u16 units)
  const int r0 = ((col & 12) << 1) | (col & 3);   // pi(col)
  int koffu[4];
#pragma unroll
  for (int c = 0; c < 4; ++c) koffu[c] = r0 * 128 + (((c * 4 + quad) ^ col) << 3);
  const int voffu = col * 32 + ((quad ^ (col & 3)) << 3);

  // ---- prologue: stage tile 0 into buf0 ----
#pragma unroll
  for (int j = 0; j < 2; ++j) {
    gl16(ksrc[j], &Kls[(wave * 2 + j) * 512]);
    gl16(vsrc[j], &Vls[(wave * 2 + j) * 512]);
  }
  int ts = 1;   // next tile to stage
#pragma unroll
  for (int j = 0; j < 2; ++j) { ksrc[j] += 32 * DMODEL; vsrc[j] += 32; }

  f32x4 accO[8];
#pragma unroll
  for (int c = 0; c < 8; ++c) accO[c] = (f32x4){0.f, 0.f, 0.f, 0.f};
  float m_run = -1e30f, l_run = 0.f;

#define AITER(CUR, LAST)                                                       \
  do {                                                                         \
    if (!(LAST)) {                                                             \
      _Pragma("unroll") for (int j = 0; j < 2; ++j) {                          \
        gl16(ksrc[j], &Kls[((CUR) ^ 1) * 4096 + (wave * 2 + j) * 512]);        \
        gl16(vsrc[j], &Vls[((CUR) ^ 1) * 4096 + (wave * 2 + j) * 512]);        \
      }                                                                        \
      const int dd = (ts == 55) ? jmpd : 32; ++ts;                             \
      _Pragma("unroll") for (int j = 0; j < 2; ++j) {                          \
        ksrc[j] += (ptrdiff_t)dd * DMODEL; vsrc[j] += dd;                      \
      }                                                                        \
    }                                                                          \
    asm volatile("s_waitcnt vmcnt(%0)" ::"i"((LAST) ? 0 : 4) : "memory");      \
    __builtin_amdgcn_s_barrier();                                              \
    asm volatile("" ::: "memory");                                             \
    f32x4 s0 = (f32x4){0.f, 0.f, 0.f, 0.f}, s1 = s0;                           \
    __builtin_amdgcn_s_setprio(1);                                             \
    _Pragma("unroll") for (int c = 0; c < 4; ++c) {                            \
      bf16x8 ka0 = *(const bf16x8*)&Kls[(CUR) * 4096 + koffu[c]];              \
      bf16x8 ka1 = *(const bf16x8*)&Kls[(CUR) * 4096 + koffu[c] + 512];        \
      s0 = __builtin_amdgcn_mfma_f32_16x16x32_bf16(ka0, qfrag[c], s0, 0, 0, 0);\
      s1 = __builtin_amdgcn_mfma_f32_16x16x32_bf16(ka1, qfrag[c], s1, 0, 0, 0);\
    }                                                                          \
    __builtin_amdgcn_s_setprio(0);                                             \
    float lmax = fmaxf(fmaxf(fmaxf(s0[0], s0[1]), fmaxf(s0[2], s0[3])),        \
                       fmaxf(fmaxf(s1[0], s1[1]), fmaxf(s1[2], s1[3])));       \
    lmax = fmaxf(lmax, __shfl_xor(lmax, 16));                                  \
    lmax = fmaxf(lmax, __shfl_xor(lmax, 32));                                  \
    if (__any(lmax > m_run + 8.f)) {                                           \
      const float mnew = fmaxf(m_run, lmax);                                   \
      const float alpha = exp2fast(m_run - mnew);                              \
      _Pragma("unroll") for (int c = 0; c < 8; ++c) {                          \
        accO[c][0] *= alpha; accO[c][1] *= alpha;                              \
        accO[c][2] *= alpha; accO[c][3] *= alpha;                              \
      }                                                                        \
      l_run *= alpha;                                                          \
      m_run = mnew;                                                            \
    }                                                                          \
    float ps = 0.f;                                                            \
    _Pragma("unroll") for (int r = 0; r < 4; ++r) {                            \
      s0[r] = exp2fast(s0[r] - m_run); s1[r] = exp2fast(s1[r] - m_run);        \
      ps += s0[r] + s1[r];                                                     \
    }                                                                          \
    union { u32 w[4]; bf16x8 v; } pu;                                          \
    asm("v_cvt_pk_bf16_f32 %0, %1, %2" : "=v"(pu.w[0]) : "v"(s0[0]), "v"(s0[1])); \
    asm("v_cvt_pk_bf16_f32 %0, %1, %2" : "=v"(pu.w[1]) : "v"(s0[2]), "v"(s0[3])); \
    asm("v_cvt_pk_bf16_f32 %0, %1, %2" : "=v"(pu.w[2]) : "v"(s1[0]), "v"(s1[1])); \
    asm("v_cvt_pk_bf16_f32 %0, %1, %2" : "=v"(pu.w[3]) : "v"(s1[2]), "v"(s1[3])); \
    __builtin_amdgcn_s_setprio(1);                                             \
    _Pragma("unroll") for (int c = 0; c < 8; ++c) {                            \
      bf16x8 va = *(const bf16x8*)&Vls[(CUR) * 4096 + voffu + c * 512];        \
      accO[c] = __builtin_amdgcn_mfma_f32_16x16x32_bf16(va, pu.v, accO[c], 0, 0, 0); \
    }                                                                          \
    __builtin_amdgcn_s_setprio(0);                                             \
    if (!(LAST)) {                                                             \
      asm volatile("" ::: "memory");                                           \
      __builtin_amdgcn_s_barrier();                                            \
      asm volatile("" ::: "memory");                                           \
    }                                                                          \
    ps += __shfl_xor(ps, 16);                                                  \
    ps += __shfl_xor(ps, 32);                                                  \
    l_run += ps;                                                               \
  } while (0)

  for (int tt = 0; tt < 34; ++tt) {   // tiles 0..67
    AITER(0, false);
    AITER(1, false);
  }
  AITER(0, false);                    // tile 68
  AITER(1, true);                     // tile 69
#undef AITER

  const float inv = 1.0f / l_run;
  const int token = q0 + wave * 16 + col;
  u16* orow = fused + (size_t)token * DMODEL + h * HDIM;
#pragma unroll
  for (int c = 0; c < 8; ++c) {
    uint2 ov;
    ov.x = (u32)f2b(accO[c][0] * inv) | ((u32)f2b(accO[c][1] * inv) << 16);
    ov.y = (u32)f2b(accO[c][2] * inv) | ((u32)f2b(accO[c][3] * inv) << 16);
    *(uint2*)(orow + c * 16 + quad * 4) = ov;
  }
}

extern "C" void kernel_launch(void* const* d_in, const int* in_sizes, int n_in,
                              void* d_out, int out_size, void* d_ws, size_t ws_size,
                              hipStream_t stream) {
  (void)in_sizes; (void)n_in; (void)out_size; (void)ws_size;
  const float* x   = (const float*)d_in[0];
  const float* fr  = (const float*)d_in[1];
  const float* qw  = (const float*)d_in[2];
  const float* qb  = (const float*)d_in[3];
  const float* kw  = (const float*)d_in[4];
  const float* kb  = (const float*)d_in[5];
  const float* vw  = (const float*)d_in[6];
  const float* vb  = (const float*)d_in[7];
  const float* ow  = (const float*)d_in[8];
  const float* ob  = (const float*)d_in[9];
  const float* nqw = (const float*)d_in[10];
  const float* nkw = (const float*)d_in[11];

  // ws (bf16 elems): qf(->fused) | (unused) | xb | wqkv(3x1536x1536) | owb.
  // d_out (fp32, 22 MB) dead until gemm_out: kf lower 11 MB, vtb upper 11 MB.
  u16* qf   = (u16*)d_ws;
  u16* vf   = qf + (size_t)TS * DMODEL;   // unused (v goes straight to vtb)
  u16* xb   = vf + (size_t)TS * DMODEL;
  u16* wqkv = xb + (size_t)TS * DMODEL;
  u16* owb  = wqkv + (size_t)3 * DMODEL * DMODEL;
  u16* kf   = (u16*)d_out;
  u16* vtb  = (u16*)d_out + (size_t)TS * DMODEL;

  convert_bf16<<<dim3(TS * DMODEL / 8 / 256, 5), dim3(256), 0, stream>>>(
      x, qw, kw, vw, ow, xb, wqkv, owb);
  gemm_qkv<<<dim3(3 * DMODEL / 128, TS / 256), dim3(512), 0, stream>>>(
      xb, wqkv, qb, kb, vb, qf, kf, vtb);
  rmsnorm_rope<<<dim3(TS, 2), dim3(256), 0, stream>>>(qf, kf, fr, nqw, nkw);
  attn_mfma<<<dim3(TS / 64, NHEAD), dim3(256), 0, stream>>>(qf, kf, vtb, qf);
  gemm_out<<<dim3(DMODEL / 128, TS / 128), dim3(256), 0, stream>>>(
      qf, owb, ob, (float*)d_out);
}

// Round 10
// 313.072 us; speedup vs baseline: 1.0398x; 1.0398x over previous
//
#include <hip/hip_runtime.h>

#define TS 3584
#define VS 1792
#define TPF 448
#define NHEAD 12
#define HDIM 128
#define DMODEL 1536
// ATTN_SCALE * log2(e): folded into q during rmsnorm_rope so QK^T scores are
// already in log2 domain (softmax uses exp2).
#define QK_PRESCALE (0.08838834764831845f * 1.4426950408889634f)

typedef unsigned short u16;
typedef unsigned int u32;
typedef unsigned long long u64;
typedef __attribute__((ext_vector_type(8))) short bf16x8;
typedef __attribute__((ext_vector_type(4))) float f32x4;

__device__ __forceinline__ float u2f(u32 u) { union { u32 u; float f; } c; c.u = u; return c.f; }
__device__ __forceinline__ float blo(u32 u) { return u2f(u << 16); }
__device__ __forceinline__ float bhi(u32 u) { return u2f(u & 0xffff0000u); }
__device__ __forceinline__ u16 f2b(float f) {
  union { float f; u32 u; } c; c.f = f;
  return (u16)((c.u + 0x7fffu + ((c.u >> 16) & 1u)) >> 16);
}

__device__ __forceinline__ float exp2fast(float x) {
#if __has_builtin(__builtin_amdgcn_exp2f)
  return __builtin_amdgcn_exp2f(x);
#else
  float r; asm("v_exp_f32 %0, %1" : "=v"(r) : "v"(x)); return r;
#endif
}

// async global -> LDS, 16B per lane; LDS dest is wave-uniform base
// (HW writes base + lane*16), global src is per-lane (pre-swizzled).
__device__ __forceinline__ void gl16(const u16* g, u16* l) {
  __builtin_amdgcn_global_load_lds(
      (const __attribute__((address_space(1))) void*)g,
      (__attribute__((address_space(3))) void*)l, 16, 0, 0);
}

// Pack fp32 tensors to bf16 (RNE). z: 0=x, 1..3=q/k/v weights (concat), 4=o_w.
__global__ __launch_bounds__(256) void convert_bf16(
    const float* __restrict__ x, const float* __restrict__ qw,
    const float* __restrict__ kw, const float* __restrict__ vw,
    const float* __restrict__ ow, u16* __restrict__ xb,
    u16* __restrict__ wqkv, u16* __restrict__ owb) {
  const int z = blockIdx.y;
  const float* src;
  u16* dst;
  int n8;
  if (z == 0)      { src = x;  dst = xb;  n8 = TS * DMODEL / 8; }
  else if (z == 4) { src = ow; dst = owb; n8 = DMODEL * DMODEL / 8; }
  else {
    src = (z == 1) ? qw : (z == 2) ? kw : vw;
    dst = wqkv + (size_t)(z - 1) * DMODEL * DMODEL;
    n8 = DMODEL * DMODEL / 8;
  }
  const int idx = blockIdx.x * 256 + threadIdx.x;
  if (idx >= n8) return;
  const float4 a = ((const float4*)src)[2 * idx];
  const float4 b = ((const float4*)src)[2 * idx + 1];
  uint4 o;
  o.x = (u32)f2b(a.x) | ((u32)f2b(a.y) << 16);
  o.y = (u32)f2b(a.z) | ((u32)f2b(a.w) << 16);
  o.z = (u32)f2b(b.x) | ((u32)f2b(b.y) << 16);
  o.w = (u32)f2b(b.z) | ((u32)f2b(b.w) << 16);
  ((uint4*)dst)[idx] = o;
}

// MFMA NT GEMM: C[m,n] = sum_k A[m,k]*W[n,k] + bias[n]. A,W bf16 K-major, K=1536.
// 128x128 tile, BK=64, 256 thr = 4 waves, each wave 64x64 via 4x4 mfma 16x16x32.
// Staging via global_load_lds (pre-swizzled global src) + bijective XCD swizzle.
// QKV v-section blocks (exactly one head wide) write vt TRANSPOSED directly
// via a swizzled LDS bounce -> no separate transpose kernel.
// NOTE (R9): 128x128 at this 2-barrier structure beats 256x128 (measured R9 vs
// R7; matches learn_hip m103/m105: tile choice is schedule-structure-dependent).
template <bool QKV>
__global__ __launch_bounds__(256) void gemm_mfma(
    const u16* __restrict__ A, const u16* __restrict__ W,
    const float* __restrict__ b0, const float* __restrict__ b1,
    const float* __restrict__ b2,
    u16* __restrict__ o0, u16* __restrict__ o1, u16* __restrict__ o2,
    float* __restrict__ of) {
  __shared__ __align__(16) u16 SH[128 * 128];   // Als | Bls; reused by v-epilogue
  u16* const Als = SH;
  u16* const Bls = SH + 128 * 64;
  const int t = threadIdx.x;
  const int wave = t >> 6, lane = t & 63, col = lane & 15, quad = lane >> 4;
  // XCD swizzle (grids are multiples of 8 -> simple form is bijective).
  const int nwg = gridDim.x * gridDim.y;
  const int dlin = blockIdx.y * gridDim.x + blockIdx.x;
  const int wk = (dlin & 7) * (nwg >> 3) + (dlin >> 3);
  const int by = wk / gridDim.x, bx = wk - by * gridDim.x;
  const int m0 = by * 128, n0 = bx * 128;
  const int wm = (wave & 1) * 64, wn = (wave >> 1) * 64;

  // per-lane pre-swizzled staging sources: LDS linear dest idx*8 holds
  // global chunk (idx&7)^((idx>>3)&7) of row idx>>3 (matches read swizzle).
  const int srow = lane >> 3;                  // 0..7
  const int sch = (lane & 7) ^ srow;           // source chunk
  const u16* pA[4];
  const u16* pB[4];
#pragma unroll
  for (int i = 0; i < 4; ++i) {
    const int r = i * 32 + wave * 8 + srow;
    pA[i] = A + (size_t)(m0 + r) * DMODEL + sch * 8;
    pB[i] = W + (size_t)(n0 + r) * DMODEL + sch * 8;
  }

  f32x4 acc[4][4];
#pragma unroll
  for (int i = 0; i < 4; ++i)
#pragma unroll
    for (int j = 0; j < 4; ++j) acc[i][j] = (f32x4){0.f, 0.f, 0.f, 0.f};

  for (int k0 = 0; k0 < DMODEL; k0 += 64) {
    __syncthreads();
#pragma unroll
    for (int i = 0; i < 4; ++i) {
      gl16(pA[i] + k0, &Als[i * 2048 + wave * 512]);
      gl16(pB[i] + k0, &Bls[i * 2048 + wave * 512]);
    }
    __syncthreads();   // compiler drains vmcnt before s_barrier
#pragma unroll
    for (int s = 0; s < 2; ++s) {
      bf16x8 af[4], bv[4];
#pragma unroll
      for (int i = 0; i < 4; ++i) {
        const int r = wm + i * 16 + col;
        af[i] = *(const bf16x8*)&Als[r * 64 + (((s * 4 + quad) ^ (r & 7)) * 8)];
      }
#pragma unroll
      for (int j = 0; j < 4; ++j) {
        const int r = wn + j * 16 + col;
        bv[j] = *(const bf16x8*)&Bls[r * 64 + (((s * 4 + quad) ^ (r & 7)) * 8)];
      }
#pragma unroll
      for (int i = 0; i < 4; ++i)
#pragma unroll
        for (int j = 0; j < 4; ++j)
          acc[i][j] = __builtin_amdgcn_mfma_f32_16x16x32_bf16(af[i], bv[j], acc[i][j], 0, 0, 0);
    }
  }

  if constexpr (QKV) {
    const int sec = n0 / DMODEL;   // block-uniform (128-wide sections)
    if (sec == 2) {
      // ---- fused V transpose: acc -> LDS [hd][tok] (chunk-XOR swizzle) -> vt ----
      __syncthreads();             // all waves done reading Als/Bls
#pragma unroll
      for (int j = 0; j < 4; ++j) {
        const int hdl = wn + j * 16 + col;           // 0..127 (= head-local hd)
        const float bias = b2[n0 - 2 * DMODEL + hdl];
#pragma unroll
        for (int i = 0; i < 4; ++i) {
          const int tokl = wm + i * 16 + quad * 4;   // 0..124 (4 consecutive)
          u64 pk = (u64)f2b(acc[i][j][0] + bias) |
                   ((u64)f2b(acc[i][j][1] + bias) << 16) |
                   ((u64)f2b(acc[i][j][2] + bias) << 32) |
                   ((u64)f2b(acc[i][j][3] + bias) << 48);
          *(u64*)&SH[hdl * 128 + (((tokl >> 3) ^ (hdl & 15)) * 8) + (tokl & 7)] = pk;
        }
      }
      __syncthreads();
      const int hgl = (n0 - 2 * DMODEL) >> 7;        // global head
#pragma unroll
      for (int it = 0; it < 8; ++it) {
        const int idx = t + it * 256;
        const int row = idx >> 4, ch = idx & 15;
        uint4 w = *(const uint4*)&SH[row * 128 + ((ch ^ (row & 15)) * 8)];
        *(uint4*)(o2 + (size_t)(hgl * HDIM + row) * TS + m0 + ch * 8) = w;
      }
      return;
    }
    // ---- q / k sections: row-major bf16 + bias ----
    u16* dst = (sec == 0) ? o0 : o1;
    const float* bp = (sec == 0) ? b0 : b1;
#pragma unroll
    for (int j = 0; j < 4; ++j) {
      const int nn = n0 - sec * DMODEL + wn + j * 16 + col;
      const float bias = bp[nn];
#pragma unroll
      for (int i = 0; i < 4; ++i) {
        const int mb = m0 + wm + i * 16 + quad * 4;
#pragma unroll
        for (int r = 0; r < 4; ++r)
          dst[(size_t)(mb + r) * DMODEL + nn] = f2b(acc[i][j][r] + bias);
      }
    }
  } else {
#pragma unroll
    for (int j = 0; j < 4; ++j) {
      const int ng = n0 + wn + j * 16 + col;
      const float bias = b0[ng];
#pragma unroll
      for (int i = 0; i < 4; ++i) {
        const int mb = m0 + wm + i * 16 + quad * 4;
#pragma unroll
        for (int r = 0; r < 4; ++r)
          of[(size_t)(mb + r) * DMODEL + ng] = acc[i][j][r] + bias;
      }
    }
  }
}

// In-place RMSNorm(+weight) then RoPE on bf16 rows. blockIdx.x = token; y: 0=q,1=k.
__global__ __launch_bounds__(256) void rmsnorm_rope(
    u16* qbuf, u16* kbuf, const float* __restrict__ freqs,
    const float* __restrict__ nqw, const float* __restrict__ nkw) {
  const int tok = blockIdx.x;
  u32* row = (u32*)((blockIdx.y == 0 ? qbuf : kbuf) + (size_t)tok * DMODEL);
  const float* w = blockIdx.y == 0 ? nqw : nkw;
  const int t = threadIdx.x;
  const u32 u0 = row[t], u1 = row[t + 256], u2 = row[t + 512];
  float px[3] = { blo(u0), blo(u1), blo(u2) };
  float py[3] = { bhi(u0), bhi(u1), bhi(u2) };
  float ss = px[0] * px[0] + py[0] * py[0] + px[1] * px[1] + py[1] * py[1] +
             px[2] * px[2] + py[2] * py[2];
#pragma unroll
  for (int off = 32; off; off >>= 1) ss += __shfl_xor(ss, off);
  __shared__ float red[4];
  if ((t & 63) == 0) red[t >> 6] = ss;
  __syncthreads();
  float rstd = rsqrtf((red[0] + red[1] + red[2] + red[3]) * (1.0f / DMODEL) + 1e-6f);
  if (blockIdx.y == 0) rstd *= QK_PRESCALE;
  const int p = tok % VS;
  const int fi = p / TPF, rem = p % TPF, hi = rem / 28, wi = rem % 28;
#pragma unroll
  for (int jj = 0; jj < 3; ++jj) {
    const int pj = t + jj * 256;
    const int i = pj & 63;
    const int prow = (i < 22) ? fi : ((i < 43) ? hi : wi);
    const float ang = freqs[prow * 64 + i];
    float sn, cs;
    sincosf(ang, &sn, &cs);
    const float a = px[jj] * rstd * w[2 * pj], b = py[jj] * rstd * w[2 * pj + 1];
    row[pj] = (u32)f2b(a * cs - b * sn) | ((u32)f2b(a * sn + b * cs) << 16);
  }
}

// MFMA flash attention over union key set (in-view 1792 + cross-view same-frame 448).
// v8-exact (best measured ~103-105 us): KVBLK=32, K AND V double-buffered
// (prefetch distance = 1 full iteration, 2-barrier schedule), Q in registers
// (LDS 32KB), unroll x2 (compile-time buffer index), in-register P via permuted
// K rows, exp2 softmax, defer-max, setprio.
__global__ __launch_bounds__(256) void attn_mfma(
    const u16* __restrict__ q, const u16* __restrict__ k,
    const u16* __restrict__ vt, u16* __restrict__ fused) {
  __shared__ __align__(16) u16 Kls[2 * 32 * 128];   // 2 bufs x 8KB
  __shared__ __align__(16) u16 Vls[2 * 128 * 32];   // 2 bufs x 8KB
  const int t = threadIdx.x;
  const int wave = t >> 6, lane = t & 63;
  const int col = lane & 15, quad = lane >> 4;
  // XCD swizzle: 672 blocks = 8 XCDs x 84; each XCD gets a contiguous run of
  // (head, qblock) so its private L2 holds ~1.5 heads of K/V (~2.8 MB).
  const int d = blockIdx.y * 56 + blockIdx.x;
  const int wk = (d & 7) * 84 + (d >> 3);
  const int h = wk / 56;
  const int qb = wk - h * 56;
  const int q0 = qb * 64;
  const int vview = q0 / VS;
  const int fidx = (q0 % VS) / TPF;
  const int base0 = vview * VS;
  const int base1 = (1 - vview) * VS + fidx * TPF;
  const int jmpd = base1 - base0 - 1760;   // tile55 -> tile56 token delta

  // ---- Q fragments straight from global ----
  bf16x8 qfrag[4];
#pragma unroll
  for (int c = 0; c < 4; ++c)
    qfrag[c] = *(const bf16x8*)(q + (size_t)(q0 + wave * 16 + col) * DMODEL +
                                h * HDIM + ((c * 4 + quad) << 3));
  asm volatile("" ::: "memory");   // pin Q loads before K staging (vmcnt order)

  // ---- per-lane staging sources (pre-swizzled) ----
  // K: chunk swizzle k4(key)=((key>>1)&12)|(key&3); permuted read rows
  // pi(col), pi(col)+4 see XOR key4 == col -> s0/s1 = keys 8*quad..8*quad+7.
  const u16* ksrc[2];
  const u16* vsrc[2];
#pragma unroll
  for (int j = 0; j < 2; ++j) {
    const int ci = (wave * 2 + j) * 64 + lane;    // 0..511
    const int key = ci >> 4, c = ci & 15;         // key 0..31
    const int k4 = ((key >> 1) & 12) | (key & 3);
    ksrc[j] = k + (size_t)(base0 + key) * DMODEL + h * HDIM + ((c ^ k4) << 3);
    const int hd = ci >> 2, sl = ci & 3;          // hd 0..127
    vsrc[j] = vt + (size_t)(h * HDIM + hd) * TS + base0 + ((sl ^ (hd & 3)) << 3);
  }
  // loop-invariant LDS read offsets (u16 units)
  const int r0 = ((col & 12) << 1) | (col & 3);   // pi(col)
  int koffu[4];
#pragma unroll
  for (int c = 0; c < 4; ++c) koffu[c] = r0 * 128 + (((c * 4 + quad) ^ col) << 3);
  const int voffu = col * 32 + ((quad ^ (col & 3)) << 3);

  // ---- prologue: stage tile 0 into buf0 ----
#pragma unroll
  for (int j = 0; j < 2; ++j) {
    gl16(ksrc[j], &Kls[(wave * 2 + j) * 512]);
    gl16(vsrc[j], &Vls[(wave * 2 + j) * 512]);
  }
  int ts = 1;   // next tile to stage
#pragma unroll
  for (int j = 0; j < 2; ++j) { ksrc[j] += 32 * DMODEL; vsrc[j] += 32; }

  f32x4 accO[8];
#pragma unroll
  for (int c = 0; c < 8; ++c) accO[c] = (f32x4){0.f, 0.f, 0.f, 0.f};
  float m_run = -1e30f, l_run = 0.f;

#define AITER(CUR, LAST)                                                       \
  do {                                                                         \
    if (!(LAST)) {                                                             \
      _Pragma("unroll") for (int j = 0; j < 2; ++j) {                          \
        gl16(ksrc[j], &Kls[((CUR) ^ 1) * 4096 + (wave * 2 + j) * 512]);        \
        gl16(vsrc[j], &Vls[((CUR) ^ 1) * 4096 + (wave * 2 + j) * 512]);        \
      }                                                                        \
      const int dd = (ts == 55) ? jmpd : 32; ++ts;                             \
      _Pragma("unroll") for (int j = 0; j < 2; ++j) {                          \
        ksrc[j] += (ptrdiff_t)dd * DMODEL; vsrc[j] += dd;                      \
      }                                                                        \
    }                                                                          \
    asm volatile("s_waitcnt vmcnt(%0)" ::"i"((LAST) ? 0 : 4) : "memory");      \
    __builtin_amdgcn_s_barrier();                                              \
    asm volatile("" ::: "memory");                                             \
    f32x4 s0 = (f32x4){0.f, 0.f, 0.f, 0.f}, s1 = s0;                           \
    __builtin_amdgcn_s_setprio(1);                                             \
    _Pragma("unroll") for (int c = 0; c < 4; ++c) {                            \
      bf16x8 ka0 = *(const bf16x8*)&Kls[(CUR) * 4096 + koffu[c]];              \
      bf16x8 ka1 = *(const bf16x8*)&Kls[(CUR) * 4096 + koffu[c] + 512];        \
      s0 = __builtin_amdgcn_mfma_f32_16x16x32_bf16(ka0, qfrag[c], s0, 0, 0, 0);\
      s1 = __builtin_amdgcn_mfma_f32_16x16x32_bf16(ka1, qfrag[c], s1, 0, 0, 0);\
    }                                                                          \
    __builtin_amdgcn_s_setprio(0);                                             \
    float lmax = fmaxf(fmaxf(fmaxf(s0[0], s0[1]), fmaxf(s0[2], s0[3])),        \
                       fmaxf(fmaxf(s1[0], s1[1]), fmaxf(s1[2], s1[3])));       \
    lmax = fmaxf(lmax, __shfl_xor(lmax, 16));                                  \
    lmax = fmaxf(lmax, __shfl_xor(lmax, 32));                                  \
    if (__any(lmax > m_run + 8.f)) {                                           \
      const float mnew = fmaxf(m_run, lmax);                                   \
      const float alpha = exp2fast(m_run - mnew);                              \
      _Pragma("unroll") for (int c = 0; c < 8; ++c) {                          \
        accO[c][0] *= alpha; accO[c][1] *= alpha;                              \
        accO[c][2] *= alpha; accO[c][3] *= alpha;                              \
      }                                                                        \
      l_run *= alpha;                                                          \
      m_run = mnew;                                                            \
    }                                                                          \
    float ps = 0.f;                                                            \
    _Pragma("unroll") for (int r = 0; r < 4; ++r) {                            \
      s0[r] = exp2fast(s0[r] - m_run); s1[r] = exp2fast(s1[r] - m_run);        \
      ps += s0[r] + s1[r];                                                     \
    }                                                                          \
    union { u32 w[4]; bf16x8 v; } pu;                                          \
    asm("v_cvt_pk_bf16_f32 %0, %1, %2" : "=v"(pu.w[0]) : "v"(s0[0]), "v"(s0[1])); \
    asm("v_cvt_pk_bf16_f32 %0, %1, %2" : "=v"(pu.w[1]) : "v"(s0[2]), "v"(s0[3])); \
    asm("v_cvt_pk_bf16_f32 %0, %1, %2" : "=v"(pu.w[2]) : "v"(s1[0]), "v"(s1[1])); \
    asm("v_cvt_pk_bf16_f32 %0, %1, %2" : "=v"(pu.w[3]) : "v"(s1[2]), "v"(s1[3])); \
    __builtin_amdgcn_s_setprio(1);                                             \
    _Pragma("unroll") for (int c = 0; c < 8; ++c) {                            \
      bf16x8 va = *(const bf16x8*)&Vls[(CUR) * 4096 + voffu + c * 512];        \
      accO[c] = __builtin_amdgcn_mfma_f32_16x16x32_bf16(va, pu.v, accO[c], 0, 0, 0); \
    }                                                                          \
    __builtin_amdgcn_s_setprio(0);                                             \
    if (!(LAST)) {                                                             \
      asm volatile("" ::: "memory");                                           \
      __builtin_amdgcn_s_barrier();                                            \
      asm volatile("" ::: "memory");                                           \
    }                                                                          \
    ps += __shfl_xor(ps, 16);                                                  \
    ps += __shfl_xor(ps, 32);                                                  \
    l_run += ps;                                                               \
  } while (0)

  for (int tt = 0; tt < 34; ++tt) {   // tiles 0..67
    AITER(0, false);
    AITER(1, false);
  }
  AITER(0, false);                    // tile 68
  AITER(1, true);                     // tile 69
#undef AITER

  const float inv = 1.0f / l_run;
  const int token = q0 + wave * 16 + col;
  u16* orow = fused + (size_t)token * DMODEL + h * HDIM;
#pragma unroll
  for (int c = 0; c < 8; ++c) {
    uint2 ov;
    ov.x = (u32)f2b(accO[c][0] * inv) | ((u32)f2b(accO[c][1] * inv) << 16);
    ov.y = (u32)f2b(accO[c][2] * inv) | ((u32)f2b(accO[c][3] * inv) << 16);
    *(uint2*)(orow + c * 16 + quad * 4) = ov;
  }
}

extern "C" void kernel_launch(void* const* d_in, const int* in_sizes, int n_in,
                              void* d_out, int out_size, void* d_ws, size_t ws_size,
                              hipStream_t stream) {
  (void)in_sizes; (void)n_in; (void)out_size; (void)ws_size;
  const float* x   = (const float*)d_in[0];
  const float* fr  = (const float*)d_in[1];
  const float* qw  = (const float*)d_in[2];
  const float* qb  = (const float*)d_in[3];
  const float* kw  = (const float*)d_in[4];
  const float* kb  = (const float*)d_in[5];
  const float* vw  = (const float*)d_in[6];
  const float* vb  = (const float*)d_in[7];
  const float* ow  = (const float*)d_in[8];
  const float* ob  = (const float*)d_in[9];
  const float* nqw = (const float*)d_in[10];
  const float* nkw = (const float*)d_in[11];

  // ws (bf16 elems): qf(->fused) | (unused) | xb | wqkv(3x1536x1536) | owb.
  // d_out (fp32, 22 MB) dead until gemm_out: kf lower 11 MB, vtb upper 11 MB.
  u16* qf   = (u16*)d_ws;
  u16* vf   = qf + (size_t)TS * DMODEL;   // unused (v goes straight to vtb)
  u16* xb   = vf + (size_t)TS * DMODEL;
  u16* wqkv = xb + (size_t)TS * DMODEL;
  u16* owb  = wqkv + (size_t)3 * DMODEL * DMODEL;
  u16* kf   = (u16*)d_out;
  u16* vtb  = (u16*)d_out + (size_t)TS * DMODEL;

  convert_bf16<<<dim3(TS * DMODEL / 8 / 256, 5), dim3(256), 0, stream>>>(
      x, qw, kw, vw, ow, xb, wqkv, owb);
  gemm_mfma<true><<<dim3(3 * DMODEL / 128, TS / 128), dim3(256), 0, stream>>>(
      xb, wqkv, qb, kb, vb, qf, kf, vtb, nullptr);
  rmsnorm_rope<<<dim3(TS, 2), dim3(256), 0, stream>>>(qf, kf, fr, nqw, nkw);
  attn_mfma<<<dim3(TS / 64, NHEAD), dim3(256), 0, stream>>>(qf, kf, vtb, qf);
  gemm_mfma<false><<<dim3(DMODEL / 128, TS / 128), dim3(256), 0, stream>>>(
      qf, owb, ob, nullptr, nullptr, nullptr, nullptr, nullptr, (float*)d_out);
}

// Round 11
// 301.640 us; speedup vs baseline: 1.0792x; 1.0379x over previous
//
#include <hip/hip_runtime.h>

#define TS 3584
#define VS 1792
#define TPF 448
#define NHEAD 12
#define HDIM 128
#define DMODEL 1536
// ATTN_SCALE * log2(e): folded into q during rmsnorm_rope so QK^T scores are
// already in log2 domain (softmax uses exp2).
#define QK_PRESCALE (0.08838834764831845f * 1.4426950408889634f)

typedef unsigned short u16;
typedef unsigned int u32;
typedef unsigned long long u64;
typedef __attribute__((ext_vector_type(8))) short bf16x8;
typedef __attribute__((ext_vector_type(4))) float f32x4;

__device__ __forceinline__ float u2f(u32 u) { union { u32 u; float f; } c; c.u = u; return c.f; }
__device__ __forceinline__ float blo(u32 u) { return u2f(u << 16); }
__device__ __forceinline__ float bhi(u32 u) { return u2f(u & 0xffff0000u); }
__device__ __forceinline__ u16 f2b(float f) {
  union { float f; u32 u; } c; c.f = f;
  return (u16)((c.u + 0x7fffu + ((c.u >> 16) & 1u)) >> 16);
}

__device__ __forceinline__ float exp2fast(float x) {
#if __has_builtin(__builtin_amdgcn_exp2f)
  return __builtin_amdgcn_exp2f(x);
#else
  float r; asm("v_exp_f32 %0, %1" : "=v"(r) : "v"(x)); return r;
#endif
}

// async global -> LDS, 16B per lane; LDS dest is wave-uniform base
// (HW writes base + lane*16), global src is per-lane (pre-swizzled).
__device__ __forceinline__ void gl16(const u16* g, u16* l) {
  __builtin_amdgcn_global_load_lds(
      (const __attribute__((address_space(1))) void*)g,
      (__attribute__((address_space(3))) void*)l, 16, 0, 0);
}

// Pack fp32 tensors to bf16 (RNE). z: 0=x, 1..3=q/k/v weights (concat), 4=o_w.
__global__ __launch_bounds__(256) void convert_bf16(
    const float* __restrict__ x, const float* __restrict__ qw,
    const float* __restrict__ kw, const float* __restrict__ vw,
    const float* __restrict__ ow, u16* __restrict__ xb,
    u16* __restrict__ wqkv, u16* __restrict__ owb) {
  const int z = blockIdx.y;
  const float* src;
  u16* dst;
  int n8;
  if (z == 0)      { src = x;  dst = xb;  n8 = TS * DMODEL / 8; }
  else if (z == 4) { src = ow; dst = owb; n8 = DMODEL * DMODEL / 8; }
  else {
    src = (z == 1) ? qw : (z == 2) ? kw : vw;
    dst = wqkv + (size_t)(z - 1) * DMODEL * DMODEL;
    n8 = DMODEL * DMODEL / 8;
  }
  const int idx = blockIdx.x * 256 + threadIdx.x;
  if (idx >= n8) return;
  const float4 a = ((const float4*)src)[2 * idx];
  const float4 b = ((const float4*)src)[2 * idx + 1];
  uint4 o;
  o.x = (u32)f2b(a.x) | ((u32)f2b(a.y) << 16);
  o.y = (u32)f2b(a.z) | ((u32)f2b(a.w) << 16);
  o.z = (u32)f2b(b.x) | ((u32)f2b(b.y) << 16);
  o.w = (u32)f2b(b.z) | ((u32)f2b(b.w) << 16);
  ((uint4*)dst)[idx] = o;
}

// MFMA NT GEMM: C[m,n] = sum_k A[m,k]*W[n,k] + bias[n]. A,W bf16 K-major, K=1536.
// 128x128 tile, BK=64, 256 thr = 4 waves, each wave 64x64 via 4x4 mfma 16x16x32.
// Staging via global_load_lds (pre-swizzled global src) + bijective XCD swizzle.
// QKV v-section blocks (exactly one head wide) write vt TRANSPOSED directly
// via a swizzled LDS bounce -> no separate transpose kernel.
// NOTE (R9): 128x128 at this 2-barrier structure beats 256x128 (measured R9 vs
// R7; matches learn_hip m103/m105: tile choice is schedule-structure-dependent).
template <bool QKV>
__global__ __launch_bounds__(256) void gemm_mfma(
    const u16* __restrict__ A, const u16* __restrict__ W,
    const float* __restrict__ b0, const float* __restrict__ b1,
    const float* __restrict__ b2,
    u16* __restrict__ o0, u16* __restrict__ o1, u16* __restrict__ o2,
    float* __restrict__ of) {
  __shared__ __align__(16) u16 SH[128 * 128];   // Als | Bls; reused by v-epilogue
  u16* const Als = SH;
  u16* const Bls = SH + 128 * 64;
  const int t = threadIdx.x;
  const int wave = t >> 6, lane = t & 63, col = lane & 15, quad = lane >> 4;
  // XCD swizzle (grids are multiples of 8 -> simple form is bijective).
  const int nwg = gridDim.x * gridDim.y;
  const int dlin = blockIdx.y * gridDim.x + blockIdx.x;
  const int wk = (dlin & 7) * (nwg >> 3) + (dlin >> 3);
  const int by = wk / gridDim.x, bx = wk - by * gridDim.x;
  const int m0 = by * 128, n0 = bx * 128;
  const int wm = (wave & 1) * 64, wn = (wave >> 1) * 64;

  // per-lane pre-swizzled staging sources: LDS linear dest idx*8 holds
  // global chunk (idx&7)^((idx>>3)&7) of row idx>>3 (matches read swizzle).
  const int srow = lane >> 3;                  // 0..7
  const int sch = (lane & 7) ^ srow;           // source chunk
  const u16* pA[4];
  const u16* pB[4];
#pragma unroll
  for (int i = 0; i < 4; ++i) {
    const int r = i * 32 + wave * 8 + srow;
    pA[i] = A + (size_t)(m0 + r) * DMODEL + sch * 8;
    pB[i] = W + (size_t)(n0 + r) * DMODEL + sch * 8;
  }

  f32x4 acc[4][4];
#pragma unroll
  for (int i = 0; i < 4; ++i)
#pragma unroll
    for (int j = 0; j < 4; ++j) acc[i][j] = (f32x4){0.f, 0.f, 0.f, 0.f};

  for (int k0 = 0; k0 < DMODEL; k0 += 64) {
    __syncthreads();
#pragma unroll
    for (int i = 0; i < 4; ++i) {
      gl16(pA[i] + k0, &Als[i * 2048 + wave * 512]);
      gl16(pB[i] + k0, &Bls[i * 2048 + wave * 512]);
    }
    __syncthreads();   // compiler drains vmcnt before s_barrier
#pragma unroll
    for (int s = 0; s < 2; ++s) {
      bf16x8 af[4], bv[4];
#pragma unroll
      for (int i = 0; i < 4; ++i) {
        const int r = wm + i * 16 + col;
        af[i] = *(const bf16x8*)&Als[r * 64 + (((s * 4 + quad) ^ (r & 7)) * 8)];
      }
#pragma unroll
      for (int j = 0; j < 4; ++j) {
        const int r = wn + j * 16 + col;
        bv[j] = *(const bf16x8*)&Bls[r * 64 + (((s * 4 + quad) ^ (r & 7)) * 8)];
      }
#pragma unroll
      for (int i = 0; i < 4; ++i)
#pragma unroll
        for (int j = 0; j < 4; ++j)
          acc[i][j] = __builtin_amdgcn_mfma_f32_16x16x32_bf16(af[i], bv[j], acc[i][j], 0, 0, 0);
    }
  }

  if constexpr (QKV) {
    const int sec = n0 / DMODEL;   // block-uniform (128-wide sections)
    if (sec == 2) {
      // ---- fused V transpose: acc -> LDS [hd][tok] (chunk-XOR swizzle) -> vt ----
      __syncthreads();             // all waves done reading Als/Bls
#pragma unroll
      for (int j = 0; j < 4; ++j) {
        const int hdl = wn + j * 16 + col;           // 0..127 (= head-local hd)
        const float bias = b2[n0 - 2 * DMODEL + hdl];
#pragma unroll
        for (int i = 0; i < 4; ++i) {
          const int tokl = wm + i * 16 + quad * 4;   // 0..124 (4 consecutive)
          u64 pk = (u64)f2b(acc[i][j][0] + bias) |
                   ((u64)f2b(acc[i][j][1] + bias) << 16) |
                   ((u64)f2b(acc[i][j][2] + bias) << 32) |
                   ((u64)f2b(acc[i][j][3] + bias) << 48);
          *(u64*)&SH[hdl * 128 + (((tokl >> 3) ^ (hdl & 15)) * 8) + (tokl & 7)] = pk;
        }
      }
      __syncthreads();
      const int hgl = (n0 - 2 * DMODEL) >> 7;        // global head
#pragma unroll
      for (int it = 0; it < 8; ++it) {
        const int idx = t + it * 256;
        const int row = idx >> 4, ch = idx & 15;
        uint4 w = *(const uint4*)&SH[row * 128 + ((ch ^ (row & 15)) * 8)];
        *(uint4*)(o2 + (size_t)(hgl * HDIM + row) * TS + m0 + ch * 8) = w;
      }
      return;
    }
    // ---- q / k sections: row-major bf16 + bias ----
    u16* dst = (sec == 0) ? o0 : o1;
    const float* bp = (sec == 0) ? b0 : b1;
#pragma unroll
    for (int j = 0; j < 4; ++j) {
      const int nn = n0 - sec * DMODEL + wn + j * 16 + col;
      const float bias = bp[nn];
#pragma unroll
      for (int i = 0; i < 4; ++i) {
        const int mb = m0 + wm + i * 16 + quad * 4;
#pragma unroll
        for (int r = 0; r < 4; ++r)
          dst[(size_t)(mb + r) * DMODEL + nn] = f2b(acc[i][j][r] + bias);
      }
    }
  } else {
#pragma unroll
    for (int j = 0; j < 4; ++j) {
      const int ng = n0 + wn + j * 16 + col;
      const float bias = b0[ng];
#pragma unroll
      for (int i = 0; i < 4; ++i) {
        const int mb = m0 + wm + i * 16 + quad * 4;
#pragma unroll
        for (int r = 0; r < 4; ++r)
          of[(size_t)(mb + r) * DMODEL + ng] = acc[i][j][r] + bias;
      }
    }
  }
}

// In-place RMSNorm(+weight) then RoPE on bf16 rows. blockIdx.x = token; y: 0=q,1=k.
__global__ __launch_bounds__(256) void rmsnorm_rope(
    u16* qbuf, u16* kbuf, const float* __restrict__ freqs,
    const float* __restrict__ nqw, const float* __restrict__ nkw) {
  const int tok = blockIdx.x;
  u32* row = (u32*)((blockIdx.y == 0 ? qbuf : kbuf) + (size_t)tok * DMODEL);
  const float* w = blockIdx.y == 0 ? nqw : nkw;
  const int t = threadIdx.x;
  const u32 u0 = row[t], u1 = row[t + 256], u2 = row[t + 512];
  float px[3] = { blo(u0), blo(u1), blo(u2) };
  float py[3] = { bhi(u0), bhi(u1), bhi(u2) };
  float ss = px[0] * px[0] + py[0] * py[0] + px[1] * px[1] + py[1] * py[1] +
             px[2] * px[2] + py[2] * py[2];
#pragma unroll
  for (int off = 32; off; off >>= 1) ss += __shfl_xor(ss, off);
  __shared__ float red[4];
  if ((t & 63) == 0) red[t >> 6] = ss;
  __syncthreads();
  float rstd = rsqrtf((red[0] + red[1] + red[2] + red[3]) * (1.0f / DMODEL) + 1e-6f);
  if (blockIdx.y == 0) rstd *= QK_PRESCALE;
  const int p = tok % VS;
  const int fi = p / TPF, rem = p % TPF, hi = rem / 28, wi = rem % 28;
#pragma unroll
  for (int jj = 0; jj < 3; ++jj) {
    const int pj = t + jj * 256;
    const int i = pj & 63;
    const int prow = (i < 22) ? fi : ((i < 43) ? hi : wi);
    const float ang = freqs[prow * 64 + i];
    float sn, cs;
    sincosf(ang, &sn, &cs);
    const float a = px[jj] * rstd * w[2 * pj], b = py[jj] * rstd * w[2 * pj + 1];
    row[pj] = (u32)f2b(a * cs - b * sn) | ((u32)f2b(a * sn + b * cs) << 16);
  }
}

// MFMA flash attention over union key set (in-view 1792 + cross-view same-frame 448).
// v11 = v8 schedule + lazy softmax reductions: per-lane max tested against the
// defer-max threshold WITHOUT cross-lane reduce (row-max shuffles only inside
// the rare rescale branch); per-lane partial l accumulated shuffle-free and
// reduced once after the loop. Removes 4 ds_bpermute/iter (2 of them serial on
// the QK->PV critical path).
__global__ __launch_bounds__(256) void attn_mfma(
    const u16* __restrict__ q, const u16* __restrict__ k,
    const u16* __restrict__ vt, u16* __restrict__ fused) {
  __shared__ __align__(16) u16 Kls[2 * 32 * 128];   // 2 bufs x 8KB
  __shared__ __align__(16) u16 Vls[2 * 128 * 32];   // 2 bufs x 8KB
  const int t = threadIdx.x;
  const int wave = t >> 6, lane = t & 63;
  const int col = lane & 15, quad = lane >> 4;
  // XCD swizzle: 672 blocks = 8 XCDs x 84; each XCD gets a contiguous run of
  // (head, qblock) so its private L2 holds ~1.5 heads of K/V (~2.8 MB).
  const int d = blockIdx.y * 56 + blockIdx.x;
  const int wk = (d & 7) * 84 + (d >> 3);
  const int h = wk / 56;
  const int qb = wk - h * 56;
  const int q0 = qb * 64;
  const int vview = q0 / VS;
  const int fidx = (q0 % VS) / TPF;
  const int base0 = vview * VS;
  const int base1 = (1 - vview) * VS + fidx * TPF;
  const int jmpd = base1 - base0 - 1760;   // tile55 -> tile56 token delta

  // ---- Q fragments straight from global ----
  bf16x8 qfrag[4];
#pragma unroll
  for (int c = 0; c < 4; ++c)
    qfrag[c] = *(const bf16x8*)(q + (size_t)(q0 + wave * 16 + col) * DMODEL +
                                h * HDIM + ((c * 4 + quad) << 3));
  asm volatile("" ::: "memory");   // pin Q loads before K staging (vmcnt order)

  // ---- per-lane staging sources (pre-swizzled) ----
  // K: chunk swizzle k4(key)=((key>>1)&12)|(key&3); permuted read rows
  // pi(col), pi(col)+4 see XOR key4 == col -> s0/s1 = keys 8*quad..8*quad+7.
  const u16* ksrc[2];
  const u16* vsrc[2];
#pragma unroll
  for (int j = 0; j < 2; ++j) {
    const int ci = (wave * 2 + j) * 64 + lane;    // 0..511
    const int key = ci >> 4, c = ci & 15;         // key 0..31
    const int k4 = ((key >> 1) & 12) | (key & 3);
    ksrc[j] = k + (size_t)(base0 + key) * DMODEL + h * HDIM + ((c ^ k4) << 3);
    const int hd = ci >> 2, sl = ci & 3;          // hd 0..127
    vsrc[j] = vt + (size_t)(h * HDIM + hd) * TS + base0 + ((sl ^ (hd & 3)) << 3);
  }
  // loop-invariant LDS read offsets (u16 units)
  const int r0 = ((col & 12) << 1) | (col & 3);   // pi(col)
  int koffu[4];
#pragma unroll
  for (int c = 0; c < 4; ++c) koffu[c] = r0 * 128 + (((c * 4 + quad) ^ col) << 3);
  const int voffu = col * 32 + ((quad ^ (col & 3)) << 3);

  // ---- prologue: stage tile 0 into buf0 ----
#pragma unroll
  for (int j = 0; j < 2; ++j) {
    gl16(ksrc[j], &Kls[(wave * 2 + j) * 512]);
    gl16(vsrc[j], &Vls[(wave * 2 + j) * 512]);
  }
  int ts = 1;   // next tile to stage
#pragma unroll
  for (int j = 0; j < 2; ++j) { ksrc[j] += 32 * DMODEL; vsrc[j] += 32; }

  f32x4 accO[8];
#pragma unroll
  for (int c = 0; c < 8; ++c) accO[c] = (f32x4){0.f, 0.f, 0.f, 0.f};
  float m_run = -1e30f, l_part = 0.f;   // m_run row-uniform; l_part PER-LANE

#define AITER(CUR, LAST)                                                       \
  do {                                                                         \
    if (!(LAST)) {                                                             \
      _Pragma("unroll") for (int j = 0; j < 2; ++j) {                          \
        gl16(ksrc[j], &Kls[((CUR) ^ 1) * 4096 + (wave * 2 + j) * 512]);        \
        gl16(vsrc[j], &Vls[((CUR) ^ 1) * 4096 + (wave * 2 + j) * 512]);        \
      }                                                                        \
      const int dd = (ts == 55) ? jmpd : 32; ++ts;                             \
      _Pragma("unroll") for (int j = 0; j < 2; ++j) {                          \
        ksrc[j] += (ptrdiff_t)dd * DMODEL; vsrc[j] += dd;                      \
      }                                                                        \
    }                                                                          \
    asm volatile("s_waitcnt vmcnt(%0)" ::"i"((LAST) ? 0 : 4) : "memory");      \
    __builtin_amdgcn_s_barrier();                                              \
    asm volatile("" ::: "memory");                                             \
    f32x4 s0 = (f32x4){0.f, 0.f, 0.f, 0.f}, s1 = s0;                           \
    __builtin_amdgcn_s_setprio(1);                                             \
    _Pragma("unroll") for (int c = 0; c < 4; ++c) {                            \
      bf16x8 ka0 = *(const bf16x8*)&Kls[(CUR) * 4096 + koffu[c]];              \
      bf16x8 ka1 = *(const bf16x8*)&Kls[(CUR) * 4096 + koffu[c] + 512];        \
      s0 = __builtin_amdgcn_mfma_f32_16x16x32_bf16(ka0, qfrag[c], s0, 0, 0, 0);\
      s1 = __builtin_amdgcn_mfma_f32_16x16x32_bf16(ka1, qfrag[c], s1, 0, 0, 0);\
    }                                                                          \
    __builtin_amdgcn_s_setprio(0);                                             \
    const float lmax = fmaxf(fmaxf(fmaxf(s0[0], s0[1]), fmaxf(s0[2], s0[3])),  \
                             fmaxf(fmaxf(s1[0], s1[1]), fmaxf(s1[2], s1[3]))); \
    if (__any(lmax > m_run + 8.f)) {   /* rare: reduce row max only here */    \
      float rmax = fmaxf(lmax, __shfl_xor(lmax, 16));                          \
      rmax = fmaxf(rmax, __shfl_xor(rmax, 32));                                \
      const float mnew = fmaxf(m_run, rmax);                                   \
      const float alpha = exp2fast(m_run - mnew);                              \
      _Pragma("unroll") for (int c = 0; c < 8; ++c) {                          \
        accO[c][0] *= alpha; accO[c][1] *= alpha;                              \
        accO[c][2] *= alpha; accO[c][3] *= alpha;                              \
      }                                                                        \
      l_part *= alpha;                                                         \
      m_run = mnew;                                                            \
    }                                                                          \
    _Pragma("unroll") for (int r = 0; r < 4; ++r) {                            \
      s0[r] = exp2fast(s0[r] - m_run); s1[r] = exp2fast(s1[r] - m_run);        \
      l_part += s0[r] + s1[r];                                                 \
    }                                                                          \
    union { u32 w[4]; bf16x8 v; } pu;                                          \
    asm("v_cvt_pk_bf16_f32 %0, %1, %2" : "=v"(pu.w[0]) : "v"(s0[0]), "v"(s0[1])); \
    asm("v_cvt_pk_bf16_f32 %0, %1, %2" : "=v"(pu.w[1]) : "v"(s0[2]), "v"(s0[3])); \
    asm("v_cvt_pk_bf16_f32 %0, %1, %2" : "=v"(pu.w[2]) : "v"(s1[0]), "v"(s1[1])); \
    asm("v_cvt_pk_bf16_f32 %0, %1, %2" : "=v"(pu.w[3]) : "v"(s1[2]), "v"(s1[3])); \
    __builtin_amdgcn_s_setprio(1);                                             \
    _Pragma("unroll") for (int c = 0; c < 8; ++c) {                            \
      bf16x8 va = *(const bf16x8*)&Vls[(CUR) * 4096 + voffu + c * 512];        \
      accO[c] = __builtin_amdgcn_mfma_f32_16x16x32_bf16(va, pu.v, accO[c], 0, 0, 0); \
    }                                                                          \
    __builtin_amdgcn_s_setprio(0);                                             \
    if (!(LAST)) {                                                             \
      asm volatile("" ::: "memory");                                           \
      __builtin_amdgcn_s_barrier();                                            \
      asm volatile("" ::: "memory");                                           \
    }                                                                          \
  } while (0)

  for (int tt = 0; tt < 34; ++tt) {   // tiles 0..67
    AITER(0, false);
    AITER(1, false);
  }
  AITER(0, false);                    // tile 68
  AITER(1, true);                     // tile 69
#undef AITER

  // row l = sum of the 4 per-lane partials (lanes col, col+16, col+32, col+48)
  float l_run = l_part;
  l_run += __shfl_xor(l_run, 16);
  l_run += __shfl_xor(l_run, 32);
  const float inv = 1.0f / l_run;
  const int token = q0 + wave * 16 + col;
  u16* orow = fused + (size_t)token * DMODEL + h * HDIM;
#pragma unroll
  for (int c = 0; c < 8; ++c) {
    uint2 ov;
    ov.x = (u32)f2b(accO[c][0] * inv) | ((u32)f2b(accO[c][1] * inv) << 16);
    ov.y = (u32)f2b(accO[c][2] * inv) | ((u32)f2b(accO[c][3] * inv) << 16);
    *(uint2*)(orow + c * 16 + quad * 4) = ov;
  }
}

extern "C" void kernel_launch(void* const* d_in, const int* in_sizes, int n_in,
                              void* d_out, int out_size, void* d_ws, size_t ws_size,
                              hipStream_t stream) {
  (void)in_sizes; (void)n_in; (void)out_size; (void)ws_size;
  const float* x   = (const float*)d_in[0];
  const float* fr  = (const float*)d_in[1];
  const float* qw  = (const float*)d_in[2];
  const float* qb  = (const float*)d_in[3];
  const float* kw  = (const float*)d_in[4];
  const float* kb  = (const float*)d_in[5];
  const float* vw  = (const float*)d_in[6];
  const float* vb  = (const float*)d_in[7];
  const float* ow  = (const float*)d_in[8];
  const float* ob  = (const float*)d_in[9];
  const float* nqw = (const float*)d_in[10];
  const float* nkw = (const float*)d_in[11];

  // ws (bf16 elems): qf(->fused) | (unused) | xb | wqkv(3x1536x1536) | owb.
  // d_out (fp32, 22 MB) dead until gemm_out: kf lower 11 MB, vtb upper 11 MB.
  u16* qf   = (u16*)d_ws;
  u16* vf   = qf + (size_t)TS * DMODEL;   // unused (v goes straight to vtb)
  u16* xb   = vf + (size_t)TS * DMODEL;
  u16* wqkv = xb + (size_t)TS * DMODEL;
  u16* owb  = wqkv + (size_t)3 * DMODEL * DMODEL;
  u16* kf   = (u16*)d_out;
  u16* vtb  = (u16*)d_out + (size_t)TS * DMODEL;

  convert_bf16<<<dim3(TS * DMODEL / 8 / 256, 5), dim3(256), 0, stream>>>(
      x, qw, kw, vw, ow, xb, wqkv, owb);
  gemm_mfma<true><<<dim3(3 * DMODEL / 128, TS / 128), dim3(256), 0, stream>>>(
      xb, wqkv, qb, kb, vb, qf, kf, vtb, nullptr);
  rmsnorm_rope<<<dim3(TS, 2), dim3(256), 0, stream>>>(qf, kf, fr, nqw, nkw);
  attn_mfma<<<dim3(TS / 64, NHEAD), dim3(256), 0, stream>>>(qf, kf, vtb, qf);
  gemm_mfma<false><<<dim3(DMODEL / 128, TS / 128), dim3(256), 0, stream>>>(
      qf, owb, ob, nullptr, nullptr, nullptr, nullptr, nullptr, (float*)d_out);
}

// Round 12
// 298.220 us; speedup vs baseline: 1.0916x; 1.0115x over previous
//
#include <hip/hip_runtime.h>

#define TS 3584
#define VS 1792
#define TPF 448
#define NHEAD 12
#define HDIM 128
#define DMODEL 1536
// ATTN_SCALE * log2(e): folded into q during rmsnorm_rope so QK^T scores are
// already in log2 domain (softmax uses exp2).
#define QK_PRESCALE (0.08838834764831845f * 1.4426950408889634f)

typedef unsigned short u16;
typedef unsigned int u32;
typedef unsigned long long u64;
typedef __attribute__((ext_vector_type(8))) short bf16x8;
typedef __attribute__((ext_vector_type(4))) float f32x4;

__device__ __forceinline__ float u2f(u32 u) { union { u32 u; float f; } c; c.u = u; return c.f; }
__device__ __forceinline__ float blo(u32 u) { return u2f(u << 16); }
__device__ __forceinline__ float bhi(u32 u) { return u2f(u & 0xffff0000u); }
__device__ __forceinline__ u16 f2b(float f) {
  union { float f; u32 u; } c; c.f = f;
  return (u16)((c.u + 0x7fffu + ((c.u >> 16) & 1u)) >> 16);
}

__device__ __forceinline__ float exp2fast(float x) {
#if __has_builtin(__builtin_amdgcn_exp2f)
  return __builtin_amdgcn_exp2f(x);
#else
  float r; asm("v_exp_f32 %0, %1" : "=v"(r) : "v"(x)); return r;
#endif
}

// async global -> LDS, 16B per lane; LDS dest is wave-uniform base
// (HW writes base + lane*16), global src is per-lane (pre-swizzled).
__device__ __forceinline__ void gl16(const u16* g, u16* l) {
  __builtin_amdgcn_global_load_lds(
      (const __attribute__((address_space(1))) void*)g,
      (__attribute__((address_space(3))) void*)l, 16, 0, 0);
}

// Pack fp32 tensors to bf16 (RNE). z: 0=x, 1..3=q/k/v weights (concat), 4=o_w.
__global__ __launch_bounds__(256) void convert_bf16(
    const float* __restrict__ x, const float* __restrict__ qw,
    const float* __restrict__ kw, const float* __restrict__ vw,
    const float* __restrict__ ow, u16* __restrict__ xb,
    u16* __restrict__ wqkv, u16* __restrict__ owb) {
  const int z = blockIdx.y;
  const float* src;
  u16* dst;
  int n8;
  if (z == 0)      { src = x;  dst = xb;  n8 = TS * DMODEL / 8; }
  else if (z == 4) { src = ow; dst = owb; n8 = DMODEL * DMODEL / 8; }
  else {
    src = (z == 1) ? qw : (z == 2) ? kw : vw;
    dst = wqkv + (size_t)(z - 1) * DMODEL * DMODEL;
    n8 = DMODEL * DMODEL / 8;
  }
  const int idx = blockIdx.x * 256 + threadIdx.x;
  if (idx >= n8) return;
  const float4 a = ((const float4*)src)[2 * idx];
  const float4 b = ((const float4*)src)[2 * idx + 1];
  uint4 o;
  o.x = (u32)f2b(a.x) | ((u32)f2b(a.y) << 16);
  o.y = (u32)f2b(a.z) | ((u32)f2b(a.w) << 16);
  o.z = (u32)f2b(b.x) | ((u32)f2b(b.y) << 16);
  o.w = (u32)f2b(b.z) | ((u32)f2b(b.w) << 16);
  ((uint4*)dst)[idx] = o;
}

// MFMA NT GEMM: C[m,n] = sum_k A[m,k]*W[n,k] + bias[n]. A,W bf16 K-major, K=1536.
// 128x128 tile, BK=64, 256 thr = 4 waves, each wave 64x64 via 4x4 mfma 16x16x32.
// Staging via global_load_lds (pre-swizzled global src) + bijective XCD swizzle.
// QKV v-section blocks (exactly one head wide) write vt TRANSPOSED directly
// via a swizzled LDS bounce -> no separate transpose kernel.
// NOTE (R9): 128x128 at this 2-barrier structure beats 256x128 (measured R9 vs
// R7; matches learn_hip m103/m105: tile choice is schedule-structure-dependent).
template <bool QKV>
__global__ __launch_bounds__(256) void gemm_mfma(
    const u16* __restrict__ A, const u16* __restrict__ W,
    const float* __restrict__ b0, const float* __restrict__ b1,
    const float* __restrict__ b2,
    u16* __restrict__ o0, u16* __restrict__ o1, u16* __restrict__ o2,
    float* __restrict__ of) {
  __shared__ __align__(16) u16 SH[128 * 128];   // Als | Bls; reused by v-epilogue
  u16* const Als = SH;
  u16* const Bls = SH + 128 * 64;
  const int t = threadIdx.x;
  const int wave = t >> 6, lane = t & 63, col = lane & 15, quad = lane >> 4;
  // XCD swizzle (grids are multiples of 8 -> simple form is bijective).
  const int nwg = gridDim.x * gridDim.y;
  const int dlin = blockIdx.y * gridDim.x + blockIdx.x;
  const int wk = (dlin & 7) * (nwg >> 3) + (dlin >> 3);
  const int by = wk / gridDim.x, bx = wk - by * gridDim.x;
  const int m0 = by * 128, n0 = bx * 128;
  const int wm = (wave & 1) * 64, wn = (wave >> 1) * 64;

  // per-lane pre-swizzled staging sources: LDS linear dest idx*8 holds
  // global chunk (idx&7)^((idx>>3)&7) of row idx>>3 (matches read swizzle).
  const int srow = lane >> 3;                  // 0..7
  const int sch = (lane & 7) ^ srow;           // source chunk
  const u16* pA[4];
  const u16* pB[4];
#pragma unroll
  for (int i = 0; i < 4; ++i) {
    const int r = i * 32 + wave * 8 + srow;
    pA[i] = A + (size_t)(m0 + r) * DMODEL + sch * 8;
    pB[i] = W + (size_t)(n0 + r) * DMODEL + sch * 8;
  }

  f32x4 acc[4][4];
#pragma unroll
  for (int i = 0; i < 4; ++i)
#pragma unroll
    for (int j = 0; j < 4; ++j) acc[i][j] = (f32x4){0.f, 0.f, 0.f, 0.f};

  for (int k0 = 0; k0 < DMODEL; k0 += 64) {
    __syncthreads();
#pragma unroll
    for (int i = 0; i < 4; ++i) {
      gl16(pA[i] + k0, &Als[i * 2048 + wave * 512]);
      gl16(pB[i] + k0, &Bls[i * 2048 + wave * 512]);
    }
    __syncthreads();   // compiler drains vmcnt before s_barrier
#pragma unroll
    for (int s = 0; s < 2; ++s) {
      bf16x8 af[4], bv[4];
#pragma unroll
      for (int i = 0; i < 4; ++i) {
        const int r = wm + i * 16 + col;
        af[i] = *(const bf16x8*)&Als[r * 64 + (((s * 4 + quad) ^ (r & 7)) * 8)];
      }
#pragma unroll
      for (int j = 0; j < 4; ++j) {
        const int r = wn + j * 16 + col;
        bv[j] = *(const bf16x8*)&Bls[r * 64 + (((s * 4 + quad) ^ (r & 7)) * 8)];
      }
#pragma unroll
      for (int i = 0; i < 4; ++i)
#pragma unroll
        for (int j = 0; j < 4; ++j)
          acc[i][j] = __builtin_amdgcn_mfma_f32_16x16x32_bf16(af[i], bv[j], acc[i][j], 0, 0, 0);
    }
  }

  if constexpr (QKV) {
    const int sec = n0 / DMODEL;   // block-uniform (128-wide sections)
    if (sec == 2) {
      // ---- fused V transpose: acc -> LDS [hd][tok] (chunk-XOR swizzle) -> vt ----
      __syncthreads();             // all waves done reading Als/Bls
#pragma unroll
      for (int j = 0; j < 4; ++j) {
        const int hdl = wn + j * 16 + col;           // 0..127 (= head-local hd)
        const float bias = b2[n0 - 2 * DMODEL + hdl];
#pragma unroll
        for (int i = 0; i < 4; ++i) {
          const int tokl = wm + i * 16 + quad * 4;   // 0..124 (4 consecutive)
          u64 pk = (u64)f2b(acc[i][j][0] + bias) |
                   ((u64)f2b(acc[i][j][1] + bias) << 16) |
                   ((u64)f2b(acc[i][j][2] + bias) << 32) |
                   ((u64)f2b(acc[i][j][3] + bias) << 48);
          *(u64*)&SH[hdl * 128 + (((tokl >> 3) ^ (hdl & 15)) * 8) + (tokl & 7)] = pk;
        }
      }
      __syncthreads();
      const int hgl = (n0 - 2 * DMODEL) >> 7;        // global head
#pragma unroll
      for (int it = 0; it < 8; ++it) {
        const int idx = t + it * 256;
        const int row = idx >> 4, ch = idx & 15;
        uint4 w = *(const uint4*)&SH[row * 128 + ((ch ^ (row & 15)) * 8)];
        *(uint4*)(o2 + (size_t)(hgl * HDIM + row) * TS + m0 + ch * 8) = w;
      }
      return;
    }
    // ---- q / k sections: row-major bf16 + bias ----
    u16* dst = (sec == 0) ? o0 : o1;
    const float* bp = (sec == 0) ? b0 : b1;
#pragma unroll
    for (int j = 0; j < 4; ++j) {
      const int nn = n0 - sec * DMODEL + wn + j * 16 + col;
      const float bias = bp[nn];
#pragma unroll
      for (int i = 0; i < 4; ++i) {
        const int mb = m0 + wm + i * 16 + quad * 4;
#pragma unroll
        for (int r = 0; r < 4; ++r)
          dst[(size_t)(mb + r) * DMODEL + nn] = f2b(acc[i][j][r] + bias);
      }
    }
  } else {
#pragma unroll
    for (int j = 0; j < 4; ++j) {
      const int ng = n0 + wn + j * 16 + col;
      const float bias = b0[ng];
#pragma unroll
      for (int i = 0; i < 4; ++i) {
        const int mb = m0 + wm + i * 16 + quad * 4;
#pragma unroll
        for (int r = 0; r < 4; ++r)
          of[(size_t)(mb + r) * DMODEL + ng] = acc[i][j][r] + bias;
      }
    }
  }
}

// In-place RMSNorm(+weight) then RoPE on bf16 rows. blockIdx.x = token; y: 0=q,1=k.
__global__ __launch_bounds__(256) void rmsnorm_rope(
    u16* qbuf, u16* kbuf, const float* __restrict__ freqs,
    const float* __restrict__ nqw, const float* __restrict__ nkw) {
  const int tok = blockIdx.x;
  u32* row = (u32*)((blockIdx.y == 0 ? qbuf : kbuf) + (size_t)tok * DMODEL);
  const float* w = blockIdx.y == 0 ? nqw : nkw;
  const int t = threadIdx.x;
  const u32 u0 = row[t], u1 = row[t + 256], u2 = row[t + 512];
  float px[3] = { blo(u0), blo(u1), blo(u2) };
  float py[3] = { bhi(u0), bhi(u1), bhi(u2) };
  float ss = px[0] * px[0] + py[0] * py[0] + px[1] * px[1] + py[1] * py[1] +
             px[2] * px[2] + py[2] * py[2];
#pragma unroll
  for (int off = 32; off; off >>= 1) ss += __shfl_xor(ss, off);
  __shared__ float red[4];
  if ((t & 63) == 0) red[t >> 6] = ss;
  __syncthreads();
  float rstd = rsqrtf((red[0] + red[1] + red[2] + red[3]) * (1.0f / DMODEL) + 1e-6f);
  if (blockIdx.y == 0) rstd *= QK_PRESCALE;
  const int p = tok % VS;
  const int fi = p / TPF, rem = p % TPF, hi = rem / 28, wi = rem % 28;
#pragma unroll
  for (int jj = 0; jj < 3; ++jj) {
    const int pj = t + jj * 256;
    const int i = pj & 63;
    const int prow = (i < 22) ? fi : ((i < 43) ? hi : wi);
    const float ang = freqs[prow * 64 + i];
    float sn, cs;
    sincosf(ang, &sn, &cs);
    const float a = px[jj] * rstd * w[2 * pj], b = py[jj] * rstd * w[2 * pj + 1];
    row[pj] = (u32)f2b(a * cs - b * sn) | ((u32)f2b(a * sn + b * cs) << 16);
  }
}

// MFMA flash attention over union key set (in-view 1792 + cross-view same-frame 448).
// v12 = v11 (lazy softmax reductions) + TRIPLE-buffered K/V staging: tile t+2
// prefetched each iteration (prefetch distance 2 -> ~700cy latency budget),
// steady vmcnt(8) (tiles t+1,t+2 in flight). LDS 48 KB: residency unchanged
// (grid-limited 2.6 blocks/CU < LDS cap 3).
__global__ __launch_bounds__(256) void attn_mfma(
    const u16* __restrict__ q, const u16* __restrict__ k,
    const u16* __restrict__ vt, u16* __restrict__ fused) {
  __shared__ __align__(16) u16 Kls[3 * 32 * 128];   // 3 bufs x 8KB
  __shared__ __align__(16) u16 Vls[3 * 128 * 32];   // 3 bufs x 8KB
  const int t = threadIdx.x;
  const int wave = t >> 6, lane = t & 63;
  const int col = lane & 15, quad = lane >> 4;
  // XCD swizzle: 672 blocks = 8 XCDs x 84; each XCD gets a contiguous run of
  // (head, qblock) so its private L2 holds ~1.5 heads of K/V (~2.8 MB).
  const int d = blockIdx.y * 56 + blockIdx.x;
  const int wk = (d & 7) * 84 + (d >> 3);
  const int h = wk / 56;
  const int qb = wk - h * 56;
  const int q0 = qb * 64;
  const int vview = q0 / VS;
  const int fidx = (q0 % VS) / TPF;
  const int base0 = vview * VS;
  const int base1 = (1 - vview) * VS + fidx * TPF;
  const int jmpd = base1 - base0 - 1760;   // tile55 -> tile56 token delta

  // ---- Q fragments straight from global ----
  bf16x8 qfrag[4];
#pragma unroll
  for (int c = 0; c < 4; ++c)
    qfrag[c] = *(const bf16x8*)(q + (size_t)(q0 + wave * 16 + col) * DMODEL +
                                h * HDIM + ((c * 4 + quad) << 3));
  asm volatile("" ::: "memory");   // pin Q loads before K staging (vmcnt order)

  // ---- per-lane staging sources (pre-swizzled) ----
  // K: chunk swizzle k4(key)=((key>>1)&12)|(key&3); permuted read rows
  // pi(col), pi(col)+4 see XOR key4 == col -> s0/s1 = keys 8*quad..8*quad+7.
  const u16* ksrc[2];
  const u16* vsrc[2];
#pragma unroll
  for (int j = 0; j < 2; ++j) {
    const int ci = (wave * 2 + j) * 64 + lane;    // 0..511
    const int key = ci >> 4, c = ci & 15;         // key 0..31
    const int k4 = ((key >> 1) & 12) | (key & 3);
    ksrc[j] = k + (size_t)(base0 + key) * DMODEL + h * HDIM + ((c ^ k4) << 3);
    const int hd = ci >> 2, sl = ci & 3;          // hd 0..127
    vsrc[j] = vt + (size_t)(h * HDIM + hd) * TS + base0 + ((sl ^ (hd & 3)) << 3);
  }
  // loop-invariant LDS read offsets (u16 units)
  const int r0 = ((col & 12) << 1) | (col & 3);   // pi(col)
  int koffu[4];
#pragma unroll
  for (int c = 0; c < 4; ++c) koffu[c] = r0 * 128 + (((c * 4 + quad) ^ col) << 3);
  const int voffu = col * 32 + ((quad ^ (col & 3)) << 3);

  // ---- prologue: stage tiles 0,1 into buf0,buf1 ----
#pragma unroll
  for (int j = 0; j < 2; ++j) {
    gl16(ksrc[j], &Kls[(wave * 2 + j) * 512]);
    gl16(vsrc[j], &Vls[(wave * 2 + j) * 512]);
  }
#pragma unroll
  for (int j = 0; j < 2; ++j) { ksrc[j] += 32 * DMODEL; vsrc[j] += 32; }
#pragma unroll
  for (int j = 0; j < 2; ++j) {
    gl16(ksrc[j], &Kls[4096 + (wave * 2 + j) * 512]);
    gl16(vsrc[j], &Vls[4096 + (wave * 2 + j) * 512]);
  }
  int ts = 2;   // next tile to stage
#pragma unroll
  for (int j = 0; j < 2; ++j) { ksrc[j] += 32 * DMODEL; vsrc[j] += 32; }

  f32x4 accO[8];
#pragma unroll
  for (int c = 0; c < 8; ++c) accO[c] = (f32x4){0.f, 0.f, 0.f, 0.f};
  float m_run = -1e30f, l_part = 0.f;   // m_run row-uniform; l_part PER-LANE

// CUR: buffer of current tile (compile-time). STAGE: prefetch tile ts into
// buf (CUR+2)%3. VM: vmcnt immediate (8 steady / 4 / 0 tail). ENDB: end-of-iter
// barrier (needed iff the NEXT iteration stages).
#define AITER(CUR, STAGE, VM, ENDB)                                            \
  do {                                                                         \
    if (STAGE) {                                                               \
      _Pragma("unroll") for (int j = 0; j < 2; ++j) {                          \
        gl16(ksrc[j], &Kls[(((CUR) + 2) % 3) * 4096 + (wave * 2 + j) * 512]);  \
        gl16(vsrc[j], &Vls[(((CUR) + 2) % 3) * 4096 + (wave * 2 + j) * 512]);  \
      }                                                                        \
      const int dd = (ts == 55) ? jmpd : 32; ++ts;                             \
      _Pragma("unroll") for (int j = 0; j < 2; ++j) {                          \
        ksrc[j] += (ptrdiff_t)dd * DMODEL; vsrc[j] += dd;                      \
      }                                                                        \
    }                                                                          \
    asm volatile("s_waitcnt vmcnt(%0)" ::"i"(VM) : "memory");                  \
    __builtin_amdgcn_s_barrier();                                              \
    asm volatile("" ::: "memory");                                             \
    f32x4 s0 = (f32x4){0.f, 0.f, 0.f, 0.f}, s1 = s0;                           \
    __builtin_amdgcn_s_setprio(1);                                             \
    _Pragma("unroll") for (int c = 0; c < 4; ++c) {                            \
      bf16x8 ka0 = *(const bf16x8*)&Kls[(CUR) * 4096 + koffu[c]];              \
      bf16x8 ka1 = *(const bf16x8*)&Kls[(CUR) * 4096 + koffu[c] + 512];        \
      s0 = __builtin_amdgcn_mfma_f32_16x16x32_bf16(ka0, qfrag[c], s0, 0, 0, 0);\
      s1 = __builtin_amdgcn_mfma_f32_16x16x32_bf16(ka1, qfrag[c], s1, 0, 0, 0);\
    }                                                                          \
    __builtin_amdgcn_s_setprio(0);                                             \
    const float lmax = fmaxf(fmaxf(fmaxf(s0[0], s0[1]), fmaxf(s0[2], s0[3])),  \
                             fmaxf(fmaxf(s1[0], s1[1]), fmaxf(s1[2], s1[3]))); \
    if (__any(lmax > m_run + 8.f)) {   /* rare: reduce row max only here */    \
      float rmax = fmaxf(lmax, __shfl_xor(lmax, 16));                          \
      rmax = fmaxf(rmax, __shfl_xor(rmax, 32));                                \
      const float mnew = fmaxf(m_run, rmax);                                   \
      const float alpha = exp2fast(m_run - mnew);                              \
      _Pragma("unroll") for (int c = 0; c < 8; ++c) {                          \
        accO[c][0] *= alpha; accO[c][1] *= alpha;                              \
        accO[c][2] *= alpha; accO[c][3] *= alpha;                              \
      }                                                                        \
      l_part *= alpha;                                                         \
      m_run = mnew;                                                            \
    }                                                                          \
    _Pragma("unroll") for (int r = 0; r < 4; ++r) {                            \
      s0[r] = exp2fast(s0[r] - m_run); s1[r] = exp2fast(s1[r] - m_run);        \
      l_part += s0[r] + s1[r];                                                 \
    }                                                                          \
    union { u32 w[4]; bf16x8 v; } pu;                                          \
    asm("v_cvt_pk_bf16_f32 %0, %1, %2" : "=v"(pu.w[0]) : "v"(s0[0]), "v"(s0[1])); \
    asm("v_cvt_pk_bf16_f32 %0, %1, %2" : "=v"(pu.w[1]) : "v"(s0[2]), "v"(s0[3])); \
    asm("v_cvt_pk_bf16_f32 %0, %1, %2" : "=v"(pu.w[2]) : "v"(s1[0]), "v"(s1[1])); \
    asm("v_cvt_pk_bf16_f32 %0, %1, %2" : "=v"(pu.w[3]) : "v"(s1[2]), "v"(s1[3])); \
    __builtin_amdgcn_s_setprio(1);                                             \
    _Pragma("unroll") for (int c = 0; c < 8; ++c) {                            \
      bf16x8 va = *(const bf16x8*)&Vls[(CUR) * 4096 + voffu + c * 512];        \
      accO[c] = __builtin_amdgcn_mfma_f32_16x16x32_bf16(va, pu.v, accO[c], 0, 0, 0); \
    }                                                                          \
    __builtin_amdgcn_s_setprio(0);                                             \
    if (ENDB) {                                                                \
      asm volatile("" ::: "memory");                                           \
      __builtin_amdgcn_s_barrier();                                            \
      asm volatile("" ::: "memory");                                           \
    }                                                                          \
  } while (0)

  for (int tt = 0; tt < 22; ++tt) {   // tiles 0..65
    AITER(0, 1, 8, 1);
    AITER(1, 1, 8, 1);
    AITER(2, 1, 8, 1);
  }
  AITER(0, 1, 8, 1);                  // tile 66 (stages 68)
  AITER(1, 1, 8, 0);                  // tile 67 (stages 69; next iter no stage)
  AITER(2, 0, 4, 0);                  // tile 68 (tile 69 still in flight)
  AITER(0, 0, 0, 0);                  // tile 69
#undef AITER

  // row l = sum of the 4 per-lane partials (lanes col, col+16, col+32, col+48)
  float l_run = l_part;
  l_run += __shfl_xor(l_run, 16);
  l_run += __shfl_xor(l_run, 32);
  const float inv = 1.0f / l_run;
  const int token = q0 + wave * 16 + col;
  u16* orow = fused + (size_t)token * DMODEL + h * HDIM;
#pragma unroll
  for (int c = 0; c < 8; ++c) {
    uint2 ov;
    ov.x = (u32)f2b(accO[c][0] * inv) | ((u32)f2b(accO[c][1] * inv) << 16);
    ov.y = (u32)f2b(accO[c][2] * inv) | ((u32)f2b(accO[c][3] * inv) << 16);
    *(uint2*)(orow + c * 16 + quad * 4) = ov;
  }
}

extern "C" void kernel_launch(void* const* d_in, const int* in_sizes, int n_in,
                              void* d_out, int out_size, void* d_ws, size_t ws_size,
                              hipStream_t stream) {
  (void)in_sizes; (void)n_in; (void)out_size; (void)ws_size;
  const float* x   = (const float*)d_in[0];
  const float* fr  = (const float*)d_in[1];
  const float* qw  = (const float*)d_in[2];
  const float* qb  = (const float*)d_in[3];
  const float* kw  = (const float*)d_in[4];
  const float* kb  = (const float*)d_in[5];
  const float* vw  = (const float*)d_in[6];
  const float* vb  = (const float*)d_in[7];
  const float* ow  = (const float*)d_in[8];
  const float* ob  = (const float*)d_in[9];
  const float* nqw = (const float*)d_in[10];
  const float* nkw = (const float*)d_in[11];

  // ws (bf16 elems): qf(->fused) | (unused) | xb | wqkv(3x1536x1536) | owb.
  // d_out (fp32, 22 MB) dead until gemm_out: kf lower 11 MB, vtb upper 11 MB.
  u16* qf   = (u16*)d_ws;
  u16* vf   = qf + (size_t)TS * DMODEL;   // unused (v goes straight to vtb)
  u16* xb   = vf + (size_t)TS * DMODEL;
  u16* wqkv = xb + (size_t)TS * DMODEL;
  u16* owb  = wqkv + (size_t)3 * DMODEL * DMODEL;
  u16* kf   = (u16*)d_out;
  u16* vtb  = (u16*)d_out + (size_t)TS * DMODEL;

  convert_bf16<<<dim3(TS * DMODEL / 8 / 256, 5), dim3(256), 0, stream>>>(
      x, qw, kw, vw, ow, xb, wqkv, owb);
  gemm_mfma<true><<<dim3(3 * DMODEL / 128, TS / 128), dim3(256), 0, stream>>>(
      xb, wqkv, qb, kb, vb, qf, kf, vtb, nullptr);
  rmsnorm_rope<<<dim3(TS, 2), dim3(256), 0, stream>>>(qf, kf, fr, nqw, nkw);
  attn_mfma<<<dim3(TS / 64, NHEAD), dim3(256), 0, stream>>>(qf, kf, vtb, qf);
  gemm_mfma<false><<<dim3(DMODEL / 128, TS / 128), dim3(256), 0, stream>>>(
      qf, owb, ob, nullptr, nullptr, nullptr, nullptr, nullptr, (float*)d_out);
}